// Round 2
// 399.536 us; speedup vs baseline: 1.0170x; 1.0170x over previous
//
#include <hip/hip_runtime.h>

#define Bsz 512
#define Lsz 512
#define Tsz 128
#define TAG_START 126
#define TAG_STOP 127
#define SPB 16            // sequences per block
#define UPITCH 136        // u_lds row pitch in bf16 elems (128 + 8 pad)

typedef __attribute__((ext_vector_type(8))) short short8;   // 8 bf16 = MFMA A/B frag
typedef __attribute__((ext_vector_type(4))) float f32x4;    // MFMA C/D frag

// Barrier draining ONLY LDS (lgkmcnt) - global prefetch loads stay in flight.
__device__ __forceinline__ void lds_barrier() {
  asm volatile("s_waitcnt lgkmcnt(0)\n\ts_barrier" ::: "memory");
}
__device__ __forceinline__ unsigned pack_bf16(float lo, float hi) {
  unsigned a = (__float_as_uint(lo) + 0x8000u) >> 16;
  unsigned b = (__float_as_uint(hi) + 0x8000u) & 0xFFFF0000u;
  return b | a;
}
__device__ __forceinline__ float bf16lo(unsigned d) { return __uint_as_float(d << 16); }
__device__ __forceinline__ float bf16hi(unsigned d) { return __uint_as_float(d & 0xFFFF0000u); }

// One block = 16 sequences, 512 threads = 8 waves; wave w owns M-tile w (16 rows).
// Per step per wave: P(16x16) = expT_tile(16x128) . U(128x16), ONE 4-deep MFMA chain.
// vs previous 4-wave version: per-wave on-chain VALU halved, 2 waves/SIMD so the
// SIMD interleaves one wave's VALU with the other's LDS/MFMA stalls.
// Numerics are bit-identical to the 4-wave version (same per-element op order;
// terminal reduction replayed on waves 0-3 with the exact old tree via fv_sh).
__global__ __launch_bounds__(512) void crf_fwd_kernel(
    const float* __restrict__ feats, const float* __restrict__ trans,
    const int* __restrict__ tags, const int* __restrict__ lens,
    float* __restrict__ diff_out)
{
  __shared__ __align__(16) unsigned short u_lds[2][SPB][UPITCH];
  __shared__ float fv_sh[Tsz][SPB];     // one-time terminal staging (8 KB)
  __shared__ float red[4][SPB];
  __shared__ float gold_sh[SPB];
  __shared__ int msh;

  const int g    = blockIdx.x;
  const int tid  = threadIdx.x;
  const int w    = tid >> 6;      // wave 0..7: owns M-tile w
  const int lane = tid & 63;
  const int q    = lane >> 4;     // quad
  const int s    = lane & 15;     // column: seq-in-block / MFMA n / A-row m
  const int seq  = g * SPB + s;
  const int lenc = lens[seq];
  const int lim  = lenc - 1;

  if (tid == 0) msh = 1;
  __syncthreads();
  if (tid < SPB) atomicMax(&msh, lens[g * SPB + tid]);
  for (int i = tid; i < 2 * SPB * UPITCH; i += 512)
    ((unsigned short*)u_lds)[i] = 0;
  __syncthreads();
  const int maxlen = msh;
  if (tid < SPB) u_lds[0][tid][TAG_START] = 0x3F80;   // bf16 1.0
  __syncthreads();

  // A-frag: af[c] = exp(trans[w*16+s][32c+8q+j]) bf16
  short8 af[4];
  {
    const float* tr = trans + (size_t)(w * 16 + s) * Tsz + q * 8;
    #pragma unroll
    for (int c = 0; c < 4; ++c) {
      float4 x = *(const float4*)(tr + c * 32);
      float4 y = *(const float4*)(tr + c * 32 + 4);
      union { unsigned u[4]; short8 v; } cv;
      cv.u[0] = pack_bf16(__expf(x.x), __expf(x.y));
      cv.u[1] = pack_bf16(__expf(x.z), __expf(x.w));
      cv.u[2] = pack_bf16(__expf(y.x), __expf(y.y));
      cv.u[3] = pack_bf16(__expf(y.z), __expf(y.w));
      af[c] = cv.v;
    }
  }

  // Emit pointer: lane's 4 C-entries = rows w*16+4q+[0..4), col s.
  const float* fp = feats + (size_t)seq * (Lsz * Tsz) + w * 16 + 4 * q;

  // 4-deep static ring: slot k holds emit row (t with t%4==k), clamped to lim
  float4 pa0, pa1, pa2, pa3;
  { int r1 = (1 < lim) ? 1 : lim, r2 = (2 < lim) ? 2 : lim, r3 = (3 < lim) ? 3 : lim;
    if (lim < 1) r1 = r2 = r3 = lim;
    pa0 = *(const float4*)(fp);
    pa1 = *(const float4*)(fp + ((size_t)r1 << 7));
    pa2 = *(const float4*)(fp + ((size_t)r2 << 7));
    pa3 = *(const float4*)(fp + ((size_t)r3 << 7)); }

  float ee[4] = {__expf(pa0.x), __expf(pa0.y), __expf(pa0.z), __expf(pa0.w)};

  float m_run = 0.0f, mcap = 0.0f;
  float ucap[4];
  #pragma unroll
  for (int i = 0; i < 4; ++i) ucap[i] = 1.0f;

#define STEP(T, PA, NA, BR, BW)                                                \
  { const int t_ = (T);                                                        \
    short8 bq0 = *(const short8*)&u_lds[BR][s][0 * 32 + q * 8];                \
    short8 bq1 = *(const short8*)&u_lds[BR][s][1 * 32 + q * 8];                \
    short8 bq2 = *(const short8*)&u_lds[BR][s][2 * 32 + q * 8];                \
    short8 bq3 = *(const short8*)&u_lds[BR][s][3 * 32 + q * 8];                \
    unsigned ud = *(const unsigned*)&u_lds[BR][s][0];                          \
    int tp = t_ + 4; tp = (tp < lim) ? tp : lim;                               \
    PA = *(const float4*)(fp + ((size_t)tp << 7));                             \
    f32x4 acc = {0.f, 0.f, 0.f, 0.f};                                          \
    acc = __builtin_amdgcn_mfma_f32_16x16x32_bf16(af[0], bq0, acc, 0,0,0);     \
    acc = __builtin_amdgcn_mfma_f32_16x16x32_bf16(af[1], bq1, acc, 0,0,0);     \
    acc = __builtin_amdgcn_mfma_f32_16x16x32_bf16(af[2], bq2, acc, 0,0,0);     \
    acc = __builtin_amdgcn_mfma_f32_16x16x32_bf16(af[3], bq3, acc, 0,0,0);     \
    float eta = bf16lo(ud) + bf16hi(ud);                                       \
    if (t_ == 0) eta = 1.0f;                                                   \
    float rce = __builtin_amdgcn_rcpf(eta);                                    \
    bool capt = (t_ == lim);                                                   \
    float uv[4];                                                               \
    _Pragma("unroll") for (int i = 0; i < 4; ++i)                              \
      uv[i] = acc[i] * rce * ee[i];                                            \
    _Pragma("unroll") for (int i = 0; i < 4; ++i)                              \
      ucap[i] = capt ? uv[i] : ucap[i];                                        \
    m_run += __logf(eta);                                                      \
    mcap = capt ? m_run : mcap;                                                \
    unsigned short* dst = &u_lds[BW][s][0];                                    \
    uint2 pk; pk.x = pack_bf16(uv[0], uv[1]); pk.y = pack_bf16(uv[2], uv[3]);  \
    *(uint2*)&dst[w * 16 + 4 * q] = pk;                                        \
    ee[0] = __expf(NA.x); ee[1] = __expf(NA.y);                                \
    ee[2] = __expf(NA.z); ee[3] = __expf(NA.w);                                \
    lds_barrier();                                                             \
  }

  for (int t = 0; t < maxlen; t += 4) {
    STEP(t + 0, pa0, pa1, 0, 1)
    STEP(t + 1, pa1, pa2, 1, 0)
    STEP(t + 2, pa2, pa3, 0, 1)
    STEP(t + 3, pa3, pa0, 1, 0)
  }
#undef STEP

  __syncthreads();

  // Terminal fv: each wave computes its own 4 rows (bit-identical per element),
  // stages to LDS; waves 0-3 then replay the EXACT old 8-value reduction tree.
  #pragma unroll
  for (int r = 0; r < 4; ++r) {
    int row = w * 16 + 4 * q + r;
    fv_sh[row][s] = __logf(ucap[r]) + mcap + trans[TAG_START * Tsz + row];
  }
  __syncthreads();

  float fwd_score = 0.f;
  float fvv[8];
  if (w < 4) {
    #pragma unroll
    for (int i = 0; i < 2; ++i)
      #pragma unroll
      for (int r = 0; r < 4; ++r)
        fvv[i * 4 + r] = fv_sh[(2 * w + i) * 16 + 4 * q + r][s];
    float mx = fvv[0];
    #pragma unroll
    for (int i = 1; i < 8; ++i) mx = fmaxf(mx, fvv[i]);
    mx = fmaxf(mx, __shfl_xor(mx, 16, 64));
    mx = fmaxf(mx, __shfl_xor(mx, 32, 64));
    if (q == 0) red[w][s] = mx;
  }
  __syncthreads();
  float gmx = 0.f;
  if (w < 4) gmx = fmaxf(fmaxf(red[0][s], red[1][s]), fmaxf(red[2][s], red[3][s]));
  __syncthreads();
  if (w < 4) {
    float se = 0.f;
    #pragma unroll
    for (int i = 0; i < 8; ++i) se += __expf(fvv[i] - gmx);
    se += __shfl_xor(se, 16, 64);
    se += __shfl_xor(se, 32, 64);
    if (q == 0) red[w][s] = se;
  }
  __syncthreads();
  if (w < 4)
    fwd_score = gmx + __logf((red[0][s] + red[1][s]) + (red[2][s] + red[3][s]));

  // ---- gold score: waves 0-3 exactly as before (seq 4w+q; 16 lanes per seq) ----
  if (w < 4) {
    int jj = 4 * w + q;
    int gs2 = g * SPB + jj;
    int lenj = lens[gs2];
    const int* tg = tags + (size_t)gs2 * Lsz;
    const float* fbj = feats + (size_t)gs2 * (Lsz * Tsz);
    float acc = 0.f;
    for (int pos = s; pos <= lenj; pos += 16) {
      int st = (pos == 0)    ? TAG_START : tg[pos - 1];
      int et = (pos == lenj) ? TAG_STOP  : tg[pos];
      acc += trans[et * Tsz + st];
    }
    for (int l = s; l < lenj; l += 16)
      acc += fbj[(size_t)l * Tsz + tg[l]];
    #pragma unroll
    for (int off = 1; off < 16; off <<= 1) acc += __shfl_xor(acc, off, 64);
    if (s == 0) gold_sh[jj] = acc;
  }
  __syncthreads();
  if (w == 0 && q == 0)
    diff_out[g * SPB + s] = fwd_score - gold_sh[s];
}

// loss = mean(diff)
__global__ __launch_bounds__(Bsz) void crf_final_kernel(
    const float* __restrict__ diff, float* __restrict__ out)
{
  int tid = threadIdx.x;
  float v = diff[tid];
  __shared__ float wred[8];
  float sum = v;
  #pragma unroll
  for (int off = 32; off > 0; off >>= 1) sum += __shfl_down(sum, off, 64);
  int wave = tid >> 6, lane = tid & 63;
  if (lane == 0) wred[wave] = sum;
  __syncthreads();
  if (tid == 0) {
    float t = 0.f;
    #pragma unroll
    for (int i = 0; i < 8; ++i) t += wred[i];
    out[0] = t * (1.0f / Bsz);
  }
}

extern "C" void kernel_launch(void* const* d_in, const int* in_sizes, int n_in,
                              void* d_out, int out_size, void* d_ws, size_t ws_size,
                              hipStream_t stream) {
  const float* feats = (const float*)d_in[0];
  const float* trans = (const float*)d_in[1];
  const int*   tags  = (const int*)d_in[2];
  const int*   lens  = (const int*)d_in[3];
  float* out  = (float*)d_out;
  float* diff = (float*)d_ws;

  crf_fwd_kernel<<<Bsz / SPB, 512, 0, stream>>>(feats, trans, tags, lens, diff);
  crf_final_kernel<<<1, Bsz, 0, stream>>>(diff, out);
}